// Round 1
// baseline (69.695 us; speedup 1.0000x reference)
//
#include <hip/hip_runtime.h>
#include <hip/hip_bf16.h>

// Problem: Q=4096 queries, R=16384 refs, D=128, threshold scalar.
// out[q] = min(count(dist(q,r) <= thr), 100) / 100   (top-k is unnecessary)

#define DIM 128
#define BM 128
#define BN 128
#define PAD 8                      // 8 bf16 = 16B pad per LDS row
#define LDS_STRIDE (DIM + PAD)     // 136 shorts per row (272B, 16B-aligned)

typedef __attribute__((ext_vector_type(8))) short short8;
typedef __attribute__((ext_vector_type(4))) float f32x4;

// ---------------- prep: fp32 -> bf16, row norms, zero counts ----------------
__global__ void prep_kernel(const float* __restrict__ qe, const float* __restrict__ re,
                            __hip_bfloat16* __restrict__ qb, __hip_bfloat16* __restrict__ rb,
                            float* __restrict__ qsq, float* __restrict__ rsq,
                            float* __restrict__ counts, int Q, int R) {
    int row = blockIdx.x;          // 0..Q+R-1
    int lane = threadIdx.x;        // 0..63, one wave
    const float* src;
    __hip_bfloat16* dst;
    float* nrm;
    if (row < Q) {
        src = qe + (size_t)row * DIM;
        dst = qb + (size_t)row * DIM;
        nrm = qsq + row;
        if (lane == 0) counts[row] = 0.0f;   // counts has Q entries
    } else {
        int r = row - Q;
        src = re + (size_t)r * DIM;
        dst = rb + (size_t)r * DIM;
        nrm = rsq + r;
    }
    float2 v = ((const float2*)src)[lane];   // 2 elements per lane
    float s = v.x * v.x + v.y * v.y;
    __hip_bfloat162 b;
    b.x = __float2bfloat16(v.x);
    b.y = __float2bfloat16(v.y);
    ((__hip_bfloat162*)dst)[lane] = b;
    #pragma unroll
    for (int off = 32; off > 0; off >>= 1) s += __shfl_down(s, off);
    if (lane == 0) *nrm = s;
}

// ---------------- main: tiled MFMA distance-count ----------------
__launch_bounds__(256, 2)
__global__ void dist_count_kernel(const __hip_bfloat16* __restrict__ qb,
                                  const __hip_bfloat16* __restrict__ rb,
                                  const float* __restrict__ qsq,
                                  const float* __restrict__ rsq,
                                  const float* __restrict__ thr_p,
                                  float* __restrict__ counts,
                                  int Q, int R) {
    __shared__ short As[BM * LDS_STRIDE];
    __shared__ short Bs[BN * LDS_STRIDE];

    const int tid  = threadIdx.x;      // 0..255
    const int lane = tid & 63;
    const int wave = tid >> 6;         // 0..3

    const int tileN = blockIdx.x;      // ref tile
    const int tileM = blockIdx.y;      // query tile

    // ---- stage A (128x128 bf16) and B (128x128 bf16) into LDS ----
    // thread t loads 16B chunks: row = t>>4 (+16*i), chunk = t&15
    {
        const int row0  = tid >> 4;    // 0..15
        const int chunk = tid & 15;    // 0..15
        const short* qsrc = (const short*)qb + (size_t)tileM * BM * DIM;
        const short* rsrc = (const short*)rb + (size_t)tileN * BN * DIM;
        #pragma unroll
        for (int i = 0; i < 8; ++i) {
            int r = row0 + i * 16;
            short8 av = *(const short8*)(qsrc + (size_t)r * DIM + chunk * 8);
            *(short8*)&As[r * LDS_STRIDE + chunk * 8] = av;
            short8 bv = *(const short8*)(rsrc + (size_t)r * DIM + chunk * 8);
            *(short8*)&Bs[r * LDS_STRIDE + chunk * 8] = bv;
        }
    }
    __syncthreads();

    // ---- MFMA: wave computes 64x64 subtile ----
    const int wrow = (wave >> 1) * 64;     // 0 or 64 (query dim)
    const int wcol = (wave & 1) * 64;      // 0 or 64 (ref dim)
    const int lr = lane & 15;              // fragment row/col
    const int lk = lane >> 4;              // k-group 0..3

    f32x4 acc[4][4] = {};                  // zero-initialized

    #pragma unroll
    for (int ks = 0; ks < 4; ++ks) {       // K = 128 = 4 * 32
        short8 a[4], b[4];
        #pragma unroll
        for (int mi = 0; mi < 4; ++mi)
            a[mi] = *(const short8*)&As[(wrow + mi * 16 + lr) * LDS_STRIDE + ks * 32 + lk * 8];
        #pragma unroll
        for (int ni = 0; ni < 4; ++ni)
            b[ni] = *(const short8*)&Bs[(wcol + ni * 16 + lr) * LDS_STRIDE + ks * 32 + lk * 8];
        #pragma unroll
        for (int mi = 0; mi < 4; ++mi)
            #pragma unroll
            for (int ni = 0; ni < 4; ++ni)
                acc[mi][ni] = __builtin_amdgcn_mfma_f32_16x16x32_bf16(a[mi], b[ni], acc[mi][ni], 0, 0, 0);
    }

    // ---- epilogue: sq = qs + rs - 2*dot; count(dist<=thr) per query row ----
    const float thr = *thr_p;
    const float t2 = thr * thr;
    const bool thr_ok = (thr >= 0.0f);
    const int qrow_base = tileM * BM + wrow;
    const int rcol_base = tileN * BN + wcol;

    #pragma unroll
    for (int mi = 0; mi < 4; ++mi) {
        #pragma unroll
        for (int reg = 0; reg < 4; ++reg) {
            const int row = qrow_base + mi * 16 + lk * 4 + reg;
            const float qs = qsq[row];
            float c = 0.0f;
            #pragma unroll
            for (int ni = 0; ni < 4; ++ni) {
                const int col = rcol_base + ni * 16 + lr;
                float sq = qs + rsq[col] - 2.0f * acc[mi][ni][reg];
                sq = fmaxf(sq, 0.0f);
                if (thr_ok && sq <= t2) c += 1.0f;
            }
            // reduce across the 16 lanes holding this row's 64 columns
            c += __shfl_xor(c, 1);
            c += __shfl_xor(c, 2);
            c += __shfl_xor(c, 4);
            c += __shfl_xor(c, 8);
            if (lr == 0 && c != 0.0f) atomicAdd(&counts[row], c);
        }
    }
}

// ---------------- finalize: out[q] = min(count, k) / k ----------------
__global__ void finalize_kernel(const float* __restrict__ counts,
                                float* __restrict__ out, int Q, int R) {
    int q = blockIdx.x * blockDim.x + threadIdx.x;
    if (q < Q) {
        float k = (R < 100) ? (float)R : 100.0f;
        out[q] = fminf(counts[q], k) / k;
    }
}

extern "C" void kernel_launch(void* const* d_in, const int* in_sizes, int n_in,
                              void* d_out, int out_size, void* d_ws, size_t ws_size,
                              hipStream_t stream) {
    const float* qe  = (const float*)d_in[0];
    const float* re  = (const float*)d_in[1];
    const float* thr = (const float*)d_in[2];
    float* out = (float*)d_out;

    const int Q = in_sizes[0] / DIM;   // 4096
    const int R = in_sizes[1] / DIM;   // 16384

    // workspace layout (16B-aligned slabs)
    char* ws = (char*)d_ws;
    __hip_bfloat16* qb = (__hip_bfloat16*)ws;                          // Q*DIM*2   = 1 MB
    __hip_bfloat16* rb = (__hip_bfloat16*)(ws + (size_t)Q * DIM * 2);  // R*DIM*2   = 4 MB
    float* qsq    = (float*)(ws + (size_t)(Q + R) * DIM * 2);          // Q*4
    float* rsq    = qsq + Q;                                           // R*4
    float* counts = rsq + R;                                           // Q*4

    prep_kernel<<<Q + R, 64, 0, stream>>>(qe, re, qb, rb, qsq, rsq, counts, Q, R);

    dim3 grid(R / BN, Q / BM);  // (128, 32)
    dist_count_kernel<<<grid, 256, 0, stream>>>(qb, rb, qsq, rsq, thr, counts, Q, R);

    finalize_kernel<<<(Q + 255) / 256, 256, 0, stream>>>(counts, out, Q, R);
}

// Round 2
// 37.876 us; speedup vs baseline: 1.8401x; 1.8401x over previous
//
#include <hip/hip_runtime.h>
#include <hip/hip_bf16.h>

// out[q] = min(|{r : dist(q,r) <= thr}|, 100) / 100   (top-k is unnecessary:
// any distance <= thr is among the 100 smallest unless count > 100, which clamps)
//
// Q=4096, R=16384, D=128. sq_dist = |q|^2 + |r|^2 - 2 q.r  via bf16 MFMA.

#define DIM   128
#define ROWB  256              // bytes per row: 128 bf16
#define BM    128
#define BN    128
#define NSPLIT 16              // blocks along R; each block covers R/NSPLIT refs

typedef __attribute__((ext_vector_type(8))) short short8;
typedef __attribute__((ext_vector_type(4))) float f32x4;

// ---------------- prep: fp32 -> bf16, row norms, zero counts ----------------
__global__ void prep_kernel(const float* __restrict__ qe, const float* __restrict__ re,
                            __hip_bfloat16* __restrict__ qb, __hip_bfloat16* __restrict__ rb,
                            float* __restrict__ qsq, float* __restrict__ rsq,
                            float* __restrict__ counts, int Q, int R) {
    const int wave = threadIdx.x >> 6;
    const int lane = threadIdx.x & 63;
    const int row = blockIdx.x * 4 + wave;        // one wave per row
    if (row >= Q + R) return;
    const float* src;
    __hip_bfloat16* dst;
    float* nrm;
    if (row < Q) {
        src = qe + (size_t)row * DIM;
        dst = qb + (size_t)row * DIM;
        nrm = qsq + row;
        if (lane == 0) counts[row] = 0.0f;
    } else {
        int r = row - Q;
        src = re + (size_t)r * DIM;
        dst = rb + (size_t)r * DIM;
        nrm = rsq + r;
    }
    float2 v = ((const float2*)src)[lane];
    float s = v.x * v.x + v.y * v.y;
    __hip_bfloat162 b;
    b.x = __float2bfloat16(v.x);
    b.y = __float2bfloat16(v.y);
    ((__hip_bfloat162*)dst)[lane] = b;
    #pragma unroll
    for (int off = 32; off > 0; off >>= 1) s += __shfl_down(s, off);
    if (lane == 0) *nrm = s;
}

// stage one 128x128 bf16 B-tile (32KB) into linear LDS via global_load_lds,
// with the st-swizzle applied to the GLOBAL source (rule #21: swizzle
// both-sides-or-neither; LDS dest must stay linear).
__device__ __forceinline__ void stage_tile(const char* __restrict__ rbc, int ref0,
                                           short* buf, int wave, int lane) {
    #pragma unroll
    for (int i = 0; i < 8; ++i) {
        const int chunk = wave * 8 + i;            // 0..31, 1KB per wave-call
        const int lds_byte = chunk * 1024 + lane * 16;
        const int row = lds_byte >> 8;             // 0..127
        const int col = lds_byte & 255;            // 16B-granular
        const int src_col = col ^ ((row & 7) << 4);
        const char* src = rbc + (size_t)(ref0 + row) * ROWB + src_col;
        char* dst = (char*)buf + lds_byte;
        __builtin_amdgcn_global_load_lds(
            (const __attribute__((address_space(1))) unsigned int*)src,
            (__attribute__((address_space(3))) unsigned int*)dst,
            16, 0, 0);
    }
}

// ---------------- main: A-in-registers, B double-buffered LDS ----------------
__launch_bounds__(256, 2)
__global__ void dist_count_kernel(const __hip_bfloat16* __restrict__ qb,
                                  const __hip_bfloat16* __restrict__ rb,
                                  const float* __restrict__ qsq,
                                  const float* __restrict__ rsq,
                                  const float* __restrict__ thr_p,
                                  float* __restrict__ counts,
                                  int Q, int R) {
    __shared__ short Bs[2][BN * DIM];              // 2 x 32KB

    const int tid  = threadIdx.x;
    const int lane = tid & 63;
    const int wave = tid >> 6;

    const int nsplit_base = blockIdx.x * (R / NSPLIT);   // ref range start
    const int tileM = blockIdx.y;
    const int NT = (R / NSPLIT) / BN;                    // 8 tiles per block

    const int wrow = (wave >> 1) * 64;   // wave's query sub-rows
    const int wcol = (wave & 1) * 64;    // wave's ref sub-cols (within tile)
    const int lr = lane & 15;
    const int lk = lane >> 4;

    const char* qbc = (const char*)qb;
    const char* rbc = (const char*)rb;

    // ---- A fragments for the full K=128 into registers (once per block) ----
    short8 a[4][4];                      // [ks][mi]
    #pragma unroll
    for (int ks = 0; ks < 4; ++ks)
        #pragma unroll
        for (int mi = 0; mi < 4; ++mi) {
            const int qrow = tileM * BM + wrow + mi * 16 + lr;
            a[ks][mi] = *(const short8*)(qbc + (size_t)qrow * ROWB + ks * 64 + lk * 16);
        }

    // query norms for this lane's 16 output rows
    float qn[16];
    #pragma unroll
    for (int mi = 0; mi < 4; ++mi)
        #pragma unroll
        for (int reg = 0; reg < 4; ++reg)
            qn[mi * 4 + reg] = qsq[tileM * BM + wrow + mi * 16 + lk * 4 + reg];

    const float thr = *thr_p;
    const float t2 = (thr < 0.0f) ? -1.0f : thr * thr;

    float c[16];
    #pragma unroll
    for (int i = 0; i < 16; ++i) c[i] = 0.0f;

    // ---- prologue: stage tile 0 ----
    stage_tile(rbc, nsplit_base, Bs[0], wave, lane);
    __syncthreads();

    for (int t = 0; t < NT; ++t) {
        if (t + 1 < NT)
            stage_tile(rbc, nsplit_base + (t + 1) * BN, Bs[(t + 1) & 1], wave, lane);

        const char* cur = (const char*)Bs[t & 1];

        f32x4 acc[4][4] = {};
        #pragma unroll
        for (int ks = 0; ks < 4; ++ks) {
            short8 b[4];
            #pragma unroll
            for (int ni = 0; ni < 4; ++ni) {
                const int brow = wcol + ni * 16 + lr;
                const int cb = (ks * 64 + lk * 16) ^ ((brow & 7) << 4);
                b[ni] = *(const short8*)(cur + brow * ROWB + cb);
            }
            #pragma unroll
            for (int mi = 0; mi < 4; ++mi)
                #pragma unroll
                for (int ni = 0; ni < 4; ++ni)
                    acc[mi][ni] = __builtin_amdgcn_mfma_f32_16x16x32_bf16(a[ks][mi], b[ni], acc[mi][ni], 0, 0, 0);
        }

        // epilogue: accumulate per-row hit counts in registers
        const int col0 = nsplit_base + t * BN + wcol;
        float rn[4];
        #pragma unroll
        for (int ni = 0; ni < 4; ++ni) rn[ni] = rsq[col0 + ni * 16 + lr];

        #pragma unroll
        for (int mi = 0; mi < 4; ++mi)
            #pragma unroll
            for (int reg = 0; reg < 4; ++reg) {
                const float qv = qn[mi * 4 + reg];
                #pragma unroll
                for (int ni = 0; ni < 4; ++ni) {
                    float sq = qv + rn[ni] - 2.0f * acc[mi][ni][reg];
                    sq = fmaxf(sq, 0.0f);
                    if (sq <= t2) c[mi * 4 + reg] += 1.0f;
                }
            }

        __syncthreads();   // drains vmcnt(0): next buffer staged + this buffer free
    }

    // ---- once per block: reduce 16 column-lanes, atomic only if nonzero ----
    #pragma unroll
    for (int mi = 0; mi < 4; ++mi)
        #pragma unroll
        for (int reg = 0; reg < 4; ++reg) {
            float v = c[mi * 4 + reg];
            v += __shfl_xor(v, 1);
            v += __shfl_xor(v, 2);
            v += __shfl_xor(v, 4);
            v += __shfl_xor(v, 8);
            if (lr == 0 && v != 0.0f) {
                const int row = tileM * BM + wrow + mi * 16 + lk * 4 + reg;
                atomicAdd(&counts[row], v);
            }
        }
}

// ---------------- finalize ----------------
__global__ void finalize_kernel(const float* __restrict__ counts,
                                float* __restrict__ out, int Q, int R) {
    int q = blockIdx.x * blockDim.x + threadIdx.x;
    if (q < Q) {
        float k = (R < 100) ? (float)R : 100.0f;
        out[q] = fminf(counts[q], k) / k;
    }
}

extern "C" void kernel_launch(void* const* d_in, const int* in_sizes, int n_in,
                              void* d_out, int out_size, void* d_ws, size_t ws_size,
                              hipStream_t stream) {
    const float* qe  = (const float*)d_in[0];
    const float* re  = (const float*)d_in[1];
    const float* thr = (const float*)d_in[2];
    float* out = (float*)d_out;

    const int Q = in_sizes[0] / DIM;   // 4096
    const int R = in_sizes[1] / DIM;   // 16384

    char* ws = (char*)d_ws;
    __hip_bfloat16* qb = (__hip_bfloat16*)ws;
    __hip_bfloat16* rb = (__hip_bfloat16*)(ws + (size_t)Q * DIM * 2);
    float* qsq    = (float*)(ws + (size_t)(Q + R) * DIM * 2);
    float* rsq    = qsq + Q;
    float* counts = rsq + R;

    const int rows = Q + R;
    prep_kernel<<<(rows + 3) / 4, 256, 0, stream>>>(qe, re, qb, rb, qsq, rsq, counts, Q, R);

    dim3 grid(NSPLIT, Q / BM);   // (16, 32) = 512 blocks = 2/CU
    dist_count_kernel<<<grid, 256, 0, stream>>>(qb, rb, qsq, rsq, thr, counts, Q, R);

    finalize_kernel<<<(Q + 255) / 256, 256, 0, stream>>>(counts, out, Q, R);
}